// Round 8
// baseline (602.392 us; speedup 1.0000x reference)
//
#include <hip/hip_runtime.h>
#include <hip/hip_bf16.h>

typedef __attribute__((ext_vector_type(8))) short short8;
typedef __attribute__((ext_vector_type(4))) float f32x4;
typedef __attribute__((ext_vector_type(4))) unsigned u32x4;
typedef unsigned short u16;

// Problem constants
#define BB 512     // batch
#define HH 1024    // hidden
#define TT 25      // decoder steps
#define CTB 128    // ct slices (each owns 8 hidden cols -> 48 Wc rows)
#define HSZ (BB*HH)   // elements in one h_bf buffer

// h_bf layout (A-frag tiled, per buffer): u16 index of (b, j) =
//   ((b>>4)*32 + (j>>5))*512 + (b&15)*32 + (j&31)
// -> one MFMA A-frag (16 rows x 32 cols) is a contiguous aligned 1 KB block.

__device__ __forceinline__ float sigm(float x){ return 1.f/(1.f+__expf(-x)); }
__device__ __forceinline__ float tanh_(float x){
  float e = __expf(-2.f*fabsf(x));
  float t = (1.f-e)/(1.f+e);
  return copysignf(t, x);
}
__device__ __forceinline__ u16 f2bf(float x){
  union { float f; unsigned u; } v; v.f = x;
  unsigned r = v.u + 0x7FFFu + ((v.u>>16)&1u);
  return (u16)(r>>16);
}
// 16B write-through store (visible at coherence point after vmcnt drain)
__device__ __forceinline__ void store16_wt(void* p, u32x4 v){
  asm volatile("global_store_dwordx4 %0, %1, off sc0 sc1" :: "v"(p), "v"(v) : "memory");
}

#if __has_builtin(__builtin_amdgcn_global_load_lds)
#define GLOAD_LDS16(g, l) __builtin_amdgcn_global_load_lds( \
    (const __attribute__((address_space(1))) void*)(g), \
    (__attribute__((address_space(3))) void*)(l), 16, 0, 0)
#define HAVE_GLL 1
#else
#define HAVE_GLL 0
#endif

// Wcp layout: per ct slice (8 hidden cols), 48 rows (r = gate*8 + u, gates:
// 0=gir 1=giz 2=gin 3=ghr 4=ghz 5=ghn), pre-packed in MFMA B-frag order:
// elem idx = ct*49152 + ((kit*3 + nf)*64 + lane)*8 + e
__device__ __forceinline__ size_t wc_idx(int ct, int r, int k){
  int nf = r>>4, rl = r&15, kit = k>>5, k31 = k&31;
  int lane = rl | (((k31>>3)&3)<<4);
  return (size_t)ct*49152 + ((size_t)(kit*3+nf)*64 + (size_t)lane)*8 + (k31&7);
}

// ---- prep 1: Whh -> Wcp gate rows 3..5 (+cbias), Wout -> WoT (bf16 [96][1024])
__global__ void k_prep_cast(const float* __restrict__ Whh, const float* __restrict__ bhh,
                            const float* __restrict__ Wout,
                            u16* __restrict__ Wcp, float* __restrict__ cbias,
                            u16* __restrict__ WoT){
  int bid = blockIdx.x, tid = threadIdx.x;
  if (bid < 3072){
    int g1 = bid >> 10, j = bid & 1023;
    int ct = j >> 3, u = j & 7, r = (3+g1)*8 + u;
    const float* src = Whh + (size_t)bid*1024;
    if (tid < 128){
      int k0 = tid*8;
      size_t base = wc_idx(ct, r, k0);
      #pragma unroll
      for (int i=0;i<8;i++) Wcp[base+i] = f2bf(src[k0+i]);
    }
    if (!tid) cbias[ct*48 + r] = bhh[bid];
  } else {
    int d = bid - 3072;
    for (int k = tid; k < 1024; k += 256)
      WoT[(size_t)d*1024 + k] = f2bf(Wout[(size_t)k*96 + d]);
  }
}

// ---- prep 2: Wx[n][k] = sum_d Wih[n][d]*Wout[k][d]  (out-proj folded into gi path)
__global__ void k_prep_wx(const float* __restrict__ Wih, const float* __restrict__ Wout,
                          u16* __restrict__ Wcp){
  __shared__ float sWih[32][97];
  __shared__ float sWo[64][97];
  int tid = threadIdx.x;
  int nt = blockIdx.x % 96, kt = blockIdx.x / 96;   // n-tile 32, k-tile 64
  for (int i = tid; i < 32*96; i += 256){ int r2=i/96, d=i%96; sWih[r2][d] = Wih[(size_t)(nt*32+r2)*96 + d]; }
  for (int i = tid; i < 64*96; i += 256){ int r2=i/96, d=i%96; sWo[r2][d]  = Wout[(size_t)(kt*64+r2)*96 + d]; }
  __syncthreads();
  int ni = tid & 31, kb = tid >> 5;    // thread owns 8 consecutive k
  float acc[8];
  #pragma unroll
  for (int i=0;i<8;i++) acc[i]=0.f;
  for (int d = 0; d < 96; d++){
    float a = sWih[ni][d];
    #pragma unroll
    for (int i=0;i<8;i++) acc[i] += a * sWo[kb*8 + i][d];
  }
  int n = nt*32 + ni;
  int g = n >> 10, j = n & 1023;
  int ct = j >> 3, u = j & 7, r = g*8 + u;
  size_t base = wc_idx(ct, r, kt*64 + kb*8);
  #pragma unroll
  for (int i=0;i<8;i++) Wcp[base+i] = f2bf(acc[i]);
}

// ---- prep 3: cbias gi rows: bih[n] + sum_d bout[d]*Wih[n][d]
__global__ void k_prep_cx(const float* __restrict__ Wih, const float* __restrict__ bih,
                          const float* __restrict__ bout, float* __restrict__ cbias){
  int n = blockIdx.x*256 + threadIdx.x;
  if (n >= 3072) return;
  float acc = bih[n];
  const float* wrow = Wih + (size_t)n*96;
  for (int d = 0; d < 96; d++) acc += bout[d]*wrow[d];
  int g = n >> 10, j = n & 1023;
  cbias[(j>>3)*48 + g*8 + (j&7)] = acc;
}

// ---- step 0: h1 = gru(p, 0) in fp32 (gh = bhh exactly since h=0)
// h_f32 COL-MAJOR [1024][512]; h_bf (= hbuf[0]) A-frag tiled. Block 0 resets flags.
__global__ void k_step0(const float* __restrict__ dec_in, const float* __restrict__ Wih,
                        const float* __restrict__ bih, const float* __restrict__ bhh,
                        float* __restrict__ h_f32, u16* __restrict__ h_bf,
                        unsigned* __restrict__ flags){
  if (blockIdx.x == 0 && threadIdx.x < 256) flags[threadIdx.x] = 0u;
  __shared__ float sP[64][97];
  __shared__ float sW[64][97];
  int tid = threadIdx.x;
  int bt = blockIdx.x & 7;
  int jt = blockIdx.x >> 3;
  for (int i = tid; i < 64*96; i += 256){ int r=i/96, d=i%96; sP[r][d] = dec_in[(size_t)(bt*64+r)*96 + d]; }
  int tb = tid >> 4, tj = tid & 15;
  float gg[3][4][4];
  for (int g = 0; g < 3; g++){
    __syncthreads();
    for (int i = tid; i < 64*96; i += 256){ int r=i/96, d=i%96; sW[r][d] = Wih[((size_t)g*1024 + jt*64 + r)*96 + d]; }
    __syncthreads();
    float acc[4][4];
    #pragma unroll
    for (int x=0;x<4;x++)
      #pragma unroll
      for (int y=0;y<4;y++) acc[x][y]=0.f;
    for (int d = 0; d < 96; d++){
      float a[4], wv[4];
      #pragma unroll
      for (int x=0;x<4;x++) a[x]  = sP[tb + x*16][d];
      #pragma unroll
      for (int y=0;y<4;y++) wv[y] = sW[tj + y*16][d];
      #pragma unroll
      for (int x=0;x<4;x++)
        #pragma unroll
        for (int y=0;y<4;y++) acc[x][y] += a[x]*wv[y];
    }
    #pragma unroll
    for (int x=0;x<4;x++)
      #pragma unroll
      for (int y=0;y<4;y++) gg[g][x][y] = acc[x][y];
  }
  #pragma unroll
  for (int x=0;x<4;x++)
    #pragma unroll
    for (int y=0;y<4;y++){
      int b = bt*64 + tb + x*16;
      int j = jt*64 + tj + y*16;
      float gir = gg[0][x][y] + bih[j];
      float giz = gg[1][x][y] + bih[1024+j];
      float gin = gg[2][x][y] + bih[2048+j];
      float r = sigm(gir + bhh[j]);
      float z = sigm(giz + bhh[1024+j]);
      float nn = tanh_(gin + r*bhh[2048+j]);
      float h = (1.f - z)*nn;
      h_f32[(size_t)j*512 + b] = h;
      h_bf[(size_t)(((b>>4)*32 + (j>>5))*512 + (b&15)*32 + (j&31))] = f2bf(h);
    }
}

// ---- persistent recurrence kernel: 256 blocks x 256 threads (4 waves, 1/SIMD).
// Block: batch half (256 rows) x ct slice (8 cols). Wave: 64 rows (4 A-frags).
// Fence-free sync: write-once h buffers + write-through stores + flag barrier.
__global__ __launch_bounds__(256, 1)
void k_persist5(const float* __restrict__ hf0, u16* __restrict__ hbase,
                const u16* __restrict__ Wcp, const float* __restrict__ cbias,
                unsigned* __restrict__ flags){
  __shared__ short8 sB[6144];       // 96 KB: Wc slice, staged ONCE
  int b = blockIdx.x, tid = threadIdx.x;
  int lane = tid & 63, w = tid >> 6;          // 4 waves
  int l16 = lane & 15, lk = lane >> 4;
  int r8 = b & 7;
  int bt = r8 >> 2;                           // batch half (XCDs 0-3 / 4-7)
  int ct = (b >> 3)*4 + (r8 & 3);             // slice [0,128)

  const short8* Wblk = (const short8*)Wcp + (size_t)ct*6144;
#if HAVE_GLL
  #pragma unroll
  for (int it = 0; it < 24; it++){
    int i = it*256 + tid;
    GLOAD_LDS16(Wblk + i, &sB[i]);
  }
#else
  for (int i = tid; i < 6144; i += 256) sB[i] = Wblk[i];
#endif

  float c0 = cbias[ct*48 +  0 + l16];
  float c1 = cbias[ct*48 + 16 + l16];
  float c2 = cbias[ct*48 + 32 + l16];
  bool hiB = (l16 & 8) != 0;
  int rowA = bt*256 + w*64;                   // wave owns 64 batch rows
  int rb0 = rowA >> 4;                        // first A-frag index
  int myFlag = bt*128 + ct;

  // f32 carry in registers (this block's own 8 cols x its 64 rows)
  float hold[4][4];
  if (!hiB){
    int colg = ct*8 + l16;                    // l16 < 8 here
    #pragma unroll
    for (int mf = 0; mf < 4; mf++){
      f32x4 h4 = *(const f32x4*)(hf0 + (size_t)colg*512 + rowA + mf*16 + lk*4);
      hold[mf][0]=h4[0]; hold[mf][1]=h4[1]; hold[mf][2]=h4[2]; hold[mf][3]=h4[3];
    }
  }
  __syncthreads();   // Wc staging complete

  for (int t = 1; t <= 24; ++t){
    const short8* pin = (const short8*)(hbase + (size_t)(t-1)*HSZ);
    u16* pout = hbase + (size_t)t*HSZ;

    // A base: frag m, kit -> Abase[m*2048 + kit*64]
    const short8* Abase = pin + (size_t)rb0*2048 + l16*4 + lk;

    // rings: A depth 6 (4 frags each), B depth 2 (3 frags each)
    short8 ra[6][4];
    #pragma unroll
    for (int d = 0; d < 6; d++)
      #pragma unroll
      for (int m = 0; m < 4; m++) ra[d][m] = Abase[m*2048 + d*64];
    short8 rb_[2][3];
    #pragma unroll
    for (int d = 0; d < 2; d++)
      #pragma unroll
      for (int nf = 0; nf < 3; nf++) rb_[d][nf] = sB[d*192 + nf*64 + lane];

    f32x4 acc[4][3];
    #pragma unroll
    for (int m=0;m<4;m++)
      #pragma unroll
      for (int nf=0;nf<3;nf++) acc[m][nf] = f32x4{0.f,0.f,0.f,0.f};

    #pragma unroll
    for (int kit = 0; kit < 32; kit++){
      const int sa = kit % 6, sb = kit & 1;
      short8 a0 = ra[sa][0], a1 = ra[sa][1], a2 = ra[sa][2], a3 = ra[sa][3];
      short8 b0 = rb_[sb][0], b1 = rb_[sb][1], b2 = rb_[sb][2];
      if (kit < 26){
        #pragma unroll
        for (int m = 0; m < 4; m++) ra[sa][m] = Abase[m*2048 + (kit+6)*64];
      }
      if (kit < 30){
        #pragma unroll
        for (int nf = 0; nf < 3; nf++) rb_[sb][nf] = sB[(kit+2)*192 + nf*64 + lane];
      }
      acc[0][0] = __builtin_amdgcn_mfma_f32_16x16x32_bf16(a0, b0, acc[0][0], 0,0,0);
      acc[1][0] = __builtin_amdgcn_mfma_f32_16x16x32_bf16(a1, b0, acc[1][0], 0,0,0);
      acc[2][0] = __builtin_amdgcn_mfma_f32_16x16x32_bf16(a2, b0, acc[2][0], 0,0,0);
      acc[3][0] = __builtin_amdgcn_mfma_f32_16x16x32_bf16(a3, b0, acc[3][0], 0,0,0);
      acc[0][1] = __builtin_amdgcn_mfma_f32_16x16x32_bf16(a0, b1, acc[0][1], 0,0,0);
      acc[1][1] = __builtin_amdgcn_mfma_f32_16x16x32_bf16(a1, b1, acc[1][1], 0,0,0);
      acc[2][1] = __builtin_amdgcn_mfma_f32_16x16x32_bf16(a2, b1, acc[2][1], 0,0,0);
      acc[3][1] = __builtin_amdgcn_mfma_f32_16x16x32_bf16(a3, b1, acc[3][1], 0,0,0);
      acc[0][2] = __builtin_amdgcn_mfma_f32_16x16x32_bf16(a0, b2, acc[0][2], 0,0,0);
      acc[1][2] = __builtin_amdgcn_mfma_f32_16x16x32_bf16(a1, b2, acc[1][2], 0,0,0);
      acc[2][2] = __builtin_amdgcn_mfma_f32_16x16x32_bf16(a2, b2, acc[2][2], 0,0,0);
      acc[3][2] = __builtin_amdgcn_mfma_f32_16x16x32_bf16(a3, b2, acc[3][2], 0,0,0);
    }

    // ---- gates via lane pair (l, l^8); lo: gir,gin,ghz  hi: giz,ghr,ghn
    // then in-wave 8x8 transpose -> one 16B write-through store per batch row
    #pragma unroll
    for (int mf=0; mf<4; mf++){
      #pragma unroll
      for (int j=0;j<4;j++){
        float g0 = acc[mf][0][j] + c0;
        float g1 = acc[mf][1][j] + c1;
        float g2 = acc[mf][2][j] + c2;
        float v1 = hiB ? g1 : g2;
        float w1 = __shfl_xor(v1, 8, 64);
        float rz = sigm(g0 + w1);
        float w2 = __shfl_xor(rz, 8, 64);
        float v3 = hiB ? (w2 * g2) : 0.f;
        float w3 = __shfl_xor(v3, 8, 64);
        float hnew = 0.f;
        if (!hiB){
          float nn = tanh_(g1 + w3);
          hnew = (1.f - w2)*nn + w2*hold[mf][j];
          hold[mf][j] = hnew;
        }
        float o1 = __shfl_xor(hnew, 1, 64);
        unsigned pk = ((unsigned)f2bf(o1) << 16) | (unsigned)f2bf(hnew);
        unsigned pk2 = __shfl_xor(pk, 2, 64);
        unsigned q2 = __shfl_xor(pk, 4, 64);
        unsigned q3 = __shfl_xor(pk2, 4, 64);
        if (l16 == 0){
          u32x4 vv = {pk, pk2, q2, q3};
          // byte addr = (rb0+mf)*32768 + (ct>>2)*1024 + (lk*4+j)*64 + (ct&3)*16
          store16_wt((char*)pout + (size_t)(rb0+mf)*32768 + (size_t)(ct>>2)*1024
                                 + (size_t)(lk*4+j)*64 + (size_t)(ct&3)*16, vv);
        }
      }
    }

    // ---- fence-free barrier
    __syncthreads();   // drains every wave's stores (vmcnt 0 before s_barrier)
    if (tid == 0)
      __hip_atomic_store(&flags[myFlag], (unsigned)t,
                         __ATOMIC_RELAXED, __HIP_MEMORY_SCOPE_AGENT);
    if (tid < 128){
      unsigned tgt = (unsigned)t;
      while (__hip_atomic_load(&flags[bt*128 + tid], __ATOMIC_RELAXED,
                               __HIP_MEMORY_SCOPE_AGENT) < tgt)
        __builtin_amdgcn_s_sleep(2);
    }
    __syncthreads();
  }
}

// ---- batched out-projection: pred[b][i][:] = hbuf[i][b,:] @ Wout + bout
// for all 25 i at once. 800 blocks (25 i x 32 row-tiles) x 384 thr (6 waves = 6 bn).
__global__ __launch_bounds__(384)
void k_pred(const u16* __restrict__ hbase, const u16* __restrict__ WoT,
            const float* __restrict__ bout, float* __restrict__ pred){
  int blk = blockIdx.x;
  int i = blk >> 5, rbt = blk & 31;       // i in [0,25), row-tile in [0,32)
  int tid = threadIdx.x;
  int lane = tid & 63, bn = tid >> 6;     // wave index = bn in [0,6)
  int l16 = lane & 15, lk = lane >> 4;
  const short8* Aq = (const short8*)(hbase + (size_t)i*HSZ)
                     + (size_t)rbt*2048 + l16*4 + lk;
  const short8* Bq = (const short8*)WoT + (size_t)(bn*16 + l16)*128 + lk;
  f32x4 acc = {0.f,0.f,0.f,0.f};
  #pragma unroll 8
  for (int kit = 0; kit < 32; kit++)
    acc = __builtin_amdgcn_mfma_f32_16x16x32_bf16(Aq[kit*64], Bq[kit*4], acc, 0,0,0);
  int c = bn*16 + l16;
  float bb = bout[c];
  #pragma unroll
  for (int j=0;j<4;j++){
    int row = rbt*16 + lk*4 + j;
    pred[(size_t)row*2400 + (size_t)i*96 + c] = acc[j] + bb;
  }
}

extern "C" void kernel_launch(void* const* d_in, const int* in_sizes, int n_in,
                              void* d_out, int out_size, void* d_ws, size_t ws_size,
                              hipStream_t stream){
  // inputs: 0 enc_in, 1 dec_in, 2..5 enc_* (DEAD CODE), 6 dec_Wih, 7 dec_Whh,
  //         8 dec_bih, 9 dec_bhh, 10 W_out, 11 b_out
  const float* dec_in = (const float*)d_in[1];
  const float* Wih  = (const float*)d_in[6];
  const float* Whh  = (const float*)d_in[7];
  const float* bih  = (const float*)d_in[8];
  const float* bhh  = (const float*)d_in[9];
  const float* Wout = (const float*)d_in[10];
  const float* bout = (const float*)d_in[11];
  float* pred = (float*)d_out;   // [512][25][96] fp32

  char* ws = (char*)d_ws;
  size_t off = 0;
  u16* Wcp = (u16*)(ws + off);   off += (size_t)CTB*48*1024*2;     // 12.58 MB
  u16* WoT = (u16*)(ws + off);   off += (size_t)96*1024*2;
  float* cbias = (float*)(ws + off); off += (size_t)6144*4;
  off = (off + 255) & ~(size_t)255;
  float* hf0 = (float*)(ws + off); off += (size_t)BB*HH*4;   // col-major f32 carry seed
  u16* hbase = (u16*)(ws + off);   off += (size_t)TT*HSZ*2;  // 25 write-once bf16 buffers
  off = (off + 255) & ~(size_t)255;
  unsigned* flags = (unsigned*)(ws + off); off += 1024;

  k_prep_cast<<<3168, 256, 0, stream>>>(Whh, bhh, Wout, Wcp, cbias, WoT);
  k_prep_wx  <<<1536, 256, 0, stream>>>(Wih, Wout, Wcp);
  k_prep_cx  <<<12,   256, 0, stream>>>(Wih, bih, bout, cbias);
  k_step0    <<<128,  256, 0, stream>>>(dec_in, Wih, bih, bhh, hf0, hbase, flags);

  const float* hf0_c = hf0;
  void* kargs[] = {(void*)&hf0_c, (void*)&hbase, (void*)&Wcp, (void*)&cbias,
                   (void*)&flags};
  hipLaunchCooperativeKernel((const void*)k_persist5, dim3(256), dim3(256),
                             kargs, 0, stream);

  k_pred<<<800, 384, 0, stream>>>(hbase, WoT, bout, pred);
}

// Round 9
// 562.825 us; speedup vs baseline: 1.0703x; 1.0703x over previous
//
#include <hip/hip_runtime.h>
#include <hip/hip_bf16.h>

typedef __attribute__((ext_vector_type(8))) short short8;
typedef __attribute__((ext_vector_type(4))) float f32x4;
typedef __attribute__((ext_vector_type(4))) unsigned u32x4;
typedef unsigned short u16;

// Problem constants
#define BB 512     // batch
#define HH 1024    // hidden
#define TT 25      // decoder steps
#define CTB 128    // ct slices (each owns 8 hidden cols -> 48 Wc rows)
#define HSZ (BB*HH)   // elements in one h_bf buffer

// h_bf layout (A-frag tiled, per buffer): u16 index of (b, j) =
//   ((b>>4)*32 + (j>>5))*512 + (b&15)*32 + (j&31)
// -> one MFMA A-frag (16 rows x 32 cols) is a contiguous aligned 1 KB block.

__device__ __forceinline__ float sigm(float x){ return 1.f/(1.f+__expf(-x)); }
__device__ __forceinline__ float tanh_(float x){
  float e = __expf(-2.f*fabsf(x));
  float t = (1.f-e)/(1.f+e);
  return copysignf(t, x);
}
__device__ __forceinline__ u16 f2bf(float x){
  union { float f; unsigned u; } v; v.f = x;
  unsigned r = v.u + 0x7FFFu + ((v.u>>16)&1u);
  return (u16)(r>>16);
}
// 16B write-through store (visible at coherence point after vmcnt drain)
__device__ __forceinline__ void store16_wt(void* p, u32x4 v){
  asm volatile("global_store_dwordx4 %0, %1, off sc0 sc1" :: "v"(p), "v"(v) : "memory");
}

#if __has_builtin(__builtin_amdgcn_global_load_lds)
#define GLOAD_LDS16(g, l) __builtin_amdgcn_global_load_lds( \
    (const __attribute__((address_space(1))) void*)(g), \
    (__attribute__((address_space(3))) void*)(l), 16, 0, 0)
#define HAVE_GLL 1
#else
#define HAVE_GLL 0
#endif

// Wcp layout: per ct slice (8 hidden cols), 48 rows (r = gate*8 + u, gates:
// 0=gir 1=giz 2=gin 3=ghr 4=ghz 5=ghn), pre-packed in MFMA B-frag order:
// elem idx = ct*49152 + ((kit*3 + nf)*64 + lane)*8 + e
__device__ __forceinline__ size_t wc_idx(int ct, int r, int k){
  int nf = r>>4, rl = r&15, kit = k>>5, k31 = k&31;
  int lane = rl | (((k31>>3)&3)<<4);
  return (size_t)ct*49152 + ((size_t)(kit*3+nf)*64 + (size_t)lane)*8 + (k31&7);
}

// ---- prep 1: Whh -> Wcp gate rows 3..5 (+cbias), Wout -> WoT (bf16 [96][1024])
__global__ void k_prep_cast(const float* __restrict__ Whh, const float* __restrict__ bhh,
                            const float* __restrict__ Wout,
                            u16* __restrict__ Wcp, float* __restrict__ cbias,
                            u16* __restrict__ WoT){
  int bid = blockIdx.x, tid = threadIdx.x;
  if (bid < 3072){
    int g1 = bid >> 10, j = bid & 1023;
    int ct = j >> 3, u = j & 7, r = (3+g1)*8 + u;
    const float* src = Whh + (size_t)bid*1024;
    if (tid < 128){
      int k0 = tid*8;
      size_t base = wc_idx(ct, r, k0);
      #pragma unroll
      for (int i=0;i<8;i++) Wcp[base+i] = f2bf(src[k0+i]);
    }
    if (!tid) cbias[ct*48 + r] = bhh[bid];
  } else {
    int d = bid - 3072;
    for (int k = tid; k < 1024; k += 256)
      WoT[(size_t)d*1024 + k] = f2bf(Wout[(size_t)k*96 + d]);
  }
}

// ---- prep 2: Wx[n][k] = sum_d Wih[n][d]*Wout[k][d]  (out-proj folded into gi path)
__global__ void k_prep_wx(const float* __restrict__ Wih, const float* __restrict__ Wout,
                          u16* __restrict__ Wcp){
  __shared__ float sWih[32][97];
  __shared__ float sWo[64][97];
  int tid = threadIdx.x;
  int nt = blockIdx.x % 96, kt = blockIdx.x / 96;   // n-tile 32, k-tile 64
  for (int i = tid; i < 32*96; i += 256){ int r2=i/96, d=i%96; sWih[r2][d] = Wih[(size_t)(nt*32+r2)*96 + d]; }
  for (int i = tid; i < 64*96; i += 256){ int r2=i/96, d=i%96; sWo[r2][d]  = Wout[(size_t)(kt*64+r2)*96 + d]; }
  __syncthreads();
  int ni = tid & 31, kb = tid >> 5;    // thread owns 8 consecutive k
  float acc[8];
  #pragma unroll
  for (int i=0;i<8;i++) acc[i]=0.f;
  for (int d = 0; d < 96; d++){
    float a = sWih[ni][d];
    #pragma unroll
    for (int i=0;i<8;i++) acc[i] += a * sWo[kb*8 + i][d];
  }
  int n = nt*32 + ni;
  int g = n >> 10, j = n & 1023;
  int ct = j >> 3, u = j & 7, r = g*8 + u;
  size_t base = wc_idx(ct, r, kt*64 + kb*8);
  #pragma unroll
  for (int i=0;i<8;i++) Wcp[base+i] = f2bf(acc[i]);
}

// ---- prep 3: cbias gi rows: bih[n] + sum_d bout[d]*Wih[n][d]
__global__ void k_prep_cx(const float* __restrict__ Wih, const float* __restrict__ bih,
                          const float* __restrict__ bout, float* __restrict__ cbias){
  int n = blockIdx.x*256 + threadIdx.x;
  if (n >= 3072) return;
  float acc = bih[n];
  const float* wrow = Wih + (size_t)n*96;
  for (int d = 0; d < 96; d++) acc += bout[d]*wrow[d];
  int g = n >> 10, j = n & 1023;
  cbias[(j>>3)*48 + g*8 + (j&7)] = acc;
}

// ---- step 0: h1 = gru(p, 0) in fp32 (gh = bhh exactly since h=0)
// h_f32 COL-MAJOR [1024][512]; h_bf (= hbuf[0]) A-frag tiled. Block 0 resets flags.
__global__ void k_step0(const float* __restrict__ dec_in, const float* __restrict__ Wih,
                        const float* __restrict__ bih, const float* __restrict__ bhh,
                        float* __restrict__ h_f32, u16* __restrict__ h_bf,
                        unsigned* __restrict__ flags){
  if (blockIdx.x == 0 && threadIdx.x < 256) flags[threadIdx.x] = 0u;
  __shared__ float sP[64][97];
  __shared__ float sW[64][97];
  int tid = threadIdx.x;
  int bt = blockIdx.x & 7;
  int jt = blockIdx.x >> 3;
  for (int i = tid; i < 64*96; i += 256){ int r=i/96, d=i%96; sP[r][d] = dec_in[(size_t)(bt*64+r)*96 + d]; }
  int tb = tid >> 4, tj = tid & 15;
  float gg[3][4][4];
  for (int g = 0; g < 3; g++){
    __syncthreads();
    for (int i = tid; i < 64*96; i += 256){ int r=i/96, d=i%96; sW[r][d] = Wih[((size_t)g*1024 + jt*64 + r)*96 + d]; }
    __syncthreads();
    float acc[4][4];
    #pragma unroll
    for (int x=0;x<4;x++)
      #pragma unroll
      for (int y=0;y<4;y++) acc[x][y]=0.f;
    for (int d = 0; d < 96; d++){
      float a[4], wv[4];
      #pragma unroll
      for (int x=0;x<4;x++) a[x]  = sP[tb + x*16][d];
      #pragma unroll
      for (int y=0;y<4;y++) wv[y] = sW[tj + y*16][d];
      #pragma unroll
      for (int x=0;x<4;x++)
        #pragma unroll
        for (int y=0;y<4;y++) acc[x][y] += a[x]*wv[y];
    }
    #pragma unroll
    for (int x=0;x<4;x++)
      #pragma unroll
      for (int y=0;y<4;y++) gg[g][x][y] = acc[x][y];
  }
  #pragma unroll
  for (int x=0;x<4;x++)
    #pragma unroll
    for (int y=0;y<4;y++){
      int b = bt*64 + tb + x*16;
      int j = jt*64 + tj + y*16;
      float gir = gg[0][x][y] + bih[j];
      float giz = gg[1][x][y] + bih[1024+j];
      float gin = gg[2][x][y] + bih[2048+j];
      float r = sigm(gir + bhh[j]);
      float z = sigm(giz + bhh[1024+j]);
      float nn = tanh_(gin + r*bhh[2048+j]);
      float h = (1.f - z)*nn;
      h_f32[(size_t)j*512 + b] = h;
      h_bf[(size_t)(((b>>4)*32 + (j>>5))*512 + (b&15)*32 + (j&31))] = f2bf(h);
    }
}

// ---- persistent recurrence: A-stream via global_load_lds DMA ring (depth 3 kits,
// un-sinkable by compiler), A/B reg double-buffer 1 kit ahead. 256 blk x 256 thr.
__global__ __launch_bounds__(256, 1)
void k_persist6(const float* __restrict__ hf0, u16* __restrict__ hbase,
                const u16* __restrict__ Wcp, const float* __restrict__ cbias,
                unsigned* __restrict__ flags){
  __shared__ short8 sB[6144];       // 96 KB: Wc slice, staged ONCE
  __shared__ short8 sA[4096];       // 64 KB: A ring [wave][slot(4)][frag(4)][64]
  int b = blockIdx.x, tid = threadIdx.x;
  int lane = tid & 63, w = tid >> 6;          // 4 waves
  int l16 = lane & 15, lk = lane >> 4;
  int r8 = b & 7;
  int bt = r8 >> 2;                           // batch half (XCDs 0-3 / 4-7)
  int ct = (b >> 3)*4 + (r8 & 3);             // slice [0,128)

  const short8* Wblk = (const short8*)Wcp + (size_t)ct*6144;
#if HAVE_GLL
  #pragma unroll
  for (int it = 0; it < 24; it++){
    int i = it*256 + tid;
    GLOAD_LDS16(Wblk + i, &sB[i]);
  }
#else
  for (int i = tid; i < 6144; i += 256) sB[i] = Wblk[i];
#endif

  float c0 = cbias[ct*48 +  0 + l16];
  float c1 = cbias[ct*48 + 16 + l16];
  float c2 = cbias[ct*48 + 32 + l16];
  bool hiB = (l16 & 8) != 0;
  int rowA = bt*256 + w*64;                   // wave owns 64 batch rows
  int rb0 = rowA >> 4;                        // first A-frag row-group
  int myFlag = bt*128 + ct;
  short8* sAw = &sA[w*1024];                  // wave's 16 KB ring
  int aswz = (l16<<2) | lk;                   // pre-swizzled DMA source lane offset

  // f32 carry in registers (this block's own 8 cols x its 64 rows)
  float hold[4][4];
  if (!hiB){
    int colg = ct*8 + l16;                    // l16 < 8 here
    #pragma unroll
    for (int mf = 0; mf < 4; mf++){
      f32x4 h4 = *(const f32x4*)(hf0 + (size_t)colg*512 + rowA + mf*16 + lk*4);
      hold[mf][0]=h4[0]; hold[mf][1]=h4[1]; hold[mf][2]=h4[2]; hold[mf][3]=h4[3];
    }
  }
  __syncthreads();   // Wc staging complete

  for (int t = 1; t <= 24; ++t){
    const short8* pin8 = (const short8*)(hbase + (size_t)(t-1)*HSZ);
    u16* pout = hbase + (size_t)t*HSZ;
    // DMA source for (frag m, kit k): Afrag + m*2048 + k*64   (per-lane swizzled)
    const short8* Afrag = pin8 + (size_t)rb0*2048 + aswz;

#if HAVE_GLL
    #define DMA_KIT(k, s) { \
      GLOAD_LDS16(Afrag + 0*2048 + (k)*64, sAw + (s)*256 + 0*64); \
      GLOAD_LDS16(Afrag + 1*2048 + (k)*64, sAw + (s)*256 + 1*64); \
      GLOAD_LDS16(Afrag + 2*2048 + (k)*64, sAw + (s)*256 + 2*64); \
      GLOAD_LDS16(Afrag + 3*2048 + (k)*64, sAw + (s)*256 + 3*64); }
#else
    #define DMA_KIT(k, s) { \
      sAw[(s)*256 + 0*64 + lane] = Afrag[0*2048 + (k)*64 - aswz + lane]; \
      sAw[(s)*256 + 1*64 + lane] = Afrag[1*2048 + (k)*64 - aswz + lane]; \
      sAw[(s)*256 + 2*64 + lane] = Afrag[2*2048 + (k)*64 - aswz + lane]; \
      sAw[(s)*256 + 3*64 + lane] = Afrag[3*2048 + (k)*64 - aswz + lane]; }
#endif

    // prologue: DMA kits 0,1,2 into slots 0,1,2
    DMA_KIT(0, 0); DMA_KIT(1, 1); DMA_KIT(2, 2);
    asm volatile("s_waitcnt vmcnt(8)" ::: "memory");   // kit0 arrived
    __builtin_amdgcn_sched_barrier(0);

    short8 araw[2][4], brw[2][3];
    #pragma unroll
    for (int m = 0; m < 4; m++) araw[0][m] = sAw[m*64 + lane];
    #pragma unroll
    for (int nf = 0; nf < 3; nf++) brw[0][nf] = sB[nf*64 + lane];

    f32x4 acc[4][3];
    #pragma unroll
    for (int m=0;m<4;m++)
      #pragma unroll
      for (int nf=0;nf<3;nf++) acc[m][nf] = f32x4{0.f,0.f,0.f,0.f};

    #pragma unroll
    for (int kit = 0; kit < 32; kit++){
      const int cur = kit & 1, nxt = cur ^ 1;
      if (kit < 31){
        if (kit < 30) asm volatile("s_waitcnt vmcnt(4)" ::: "memory");
        else          asm volatile("s_waitcnt vmcnt(0)" ::: "memory");
        __builtin_amdgcn_sched_barrier(0);
        const int s1 = (kit+1) & 3;
        #pragma unroll
        for (int m = 0; m < 4; m++) araw[nxt][m] = sAw[s1*256 + m*64 + lane];
        #pragma unroll
        for (int nf = 0; nf < 3; nf++) brw[nxt][nf] = sB[(kit+1)*192 + nf*64 + lane];
      }
      if (kit < 29) DMA_KIT(kit+3, (kit+3) & 3);
      acc[0][0] = __builtin_amdgcn_mfma_f32_16x16x32_bf16(araw[cur][0], brw[cur][0], acc[0][0], 0,0,0);
      acc[1][0] = __builtin_amdgcn_mfma_f32_16x16x32_bf16(araw[cur][1], brw[cur][0], acc[1][0], 0,0,0);
      acc[2][0] = __builtin_amdgcn_mfma_f32_16x16x32_bf16(araw[cur][2], brw[cur][0], acc[2][0], 0,0,0);
      acc[3][0] = __builtin_amdgcn_mfma_f32_16x16x32_bf16(araw[cur][3], brw[cur][0], acc[3][0], 0,0,0);
      acc[0][1] = __builtin_amdgcn_mfma_f32_16x16x32_bf16(araw[cur][0], brw[cur][1], acc[0][1], 0,0,0);
      acc[1][1] = __builtin_amdgcn_mfma_f32_16x16x32_bf16(araw[cur][1], brw[cur][1], acc[1][1], 0,0,0);
      acc[2][1] = __builtin_amdgcn_mfma_f32_16x16x32_bf16(araw[cur][2], brw[cur][1], acc[2][1], 0,0,0);
      acc[3][1] = __builtin_amdgcn_mfma_f32_16x16x32_bf16(araw[cur][3], brw[cur][1], acc[3][1], 0,0,0);
      acc[0][2] = __builtin_amdgcn_mfma_f32_16x16x32_bf16(araw[cur][0], brw[cur][2], acc[0][2], 0,0,0);
      acc[1][2] = __builtin_amdgcn_mfma_f32_16x16x32_bf16(araw[cur][1], brw[cur][2], acc[1][2], 0,0,0);
      acc[2][2] = __builtin_amdgcn_mfma_f32_16x16x32_bf16(araw[cur][2], brw[cur][2], acc[2][2], 0,0,0);
      acc[3][2] = __builtin_amdgcn_mfma_f32_16x16x32_bf16(araw[cur][3], brw[cur][2], acc[3][2], 0,0,0);
    }
    #undef DMA_KIT

    // ---- gates via lane pair (l, l^8); lo: gir,gin,ghz  hi: giz,ghr,ghn
    // then in-wave 8x8 transpose -> one 16B write-through store per batch row
    #pragma unroll
    for (int mf=0; mf<4; mf++){
      #pragma unroll
      for (int j=0;j<4;j++){
        float g0 = acc[mf][0][j] + c0;
        float g1 = acc[mf][1][j] + c1;
        float g2 = acc[mf][2][j] + c2;
        float v1 = hiB ? g1 : g2;
        float w1 = __shfl_xor(v1, 8, 64);
        float rz = sigm(g0 + w1);
        float w2 = __shfl_xor(rz, 8, 64);
        float v3 = hiB ? (w2 * g2) : 0.f;
        float w3 = __shfl_xor(v3, 8, 64);
        float hnew = 0.f;
        if (!hiB){
          float nn = tanh_(g1 + w3);
          hnew = (1.f - w2)*nn + w2*hold[mf][j];
          hold[mf][j] = hnew;
        }
        float o1 = __shfl_xor(hnew, 1, 64);
        unsigned pk = ((unsigned)f2bf(o1) << 16) | (unsigned)f2bf(hnew);
        unsigned pk2 = __shfl_xor(pk, 2, 64);
        unsigned q2 = __shfl_xor(pk, 4, 64);
        unsigned q3 = __shfl_xor(pk2, 4, 64);
        if (l16 == 0){
          u32x4 vv = {pk, pk2, q2, q3};
          store16_wt((char*)pout + (size_t)(rb0+mf)*32768 + (size_t)(ct>>2)*1024
                                 + (size_t)(lk*4+j)*64 + (size_t)(ct&3)*16, vv);
        }
      }
    }

    // ---- fence-free barrier
    __syncthreads();   // drains every wave's stores+DMA (vmcnt 0 before s_barrier)
    if (tid == 0)
      __hip_atomic_store(&flags[myFlag], (unsigned)t,
                         __ATOMIC_RELAXED, __HIP_MEMORY_SCOPE_AGENT);
    if (tid < 128){
      unsigned tgt = (unsigned)t;
      while (__hip_atomic_load(&flags[bt*128 + tid], __ATOMIC_RELAXED,
                               __HIP_MEMORY_SCOPE_AGENT) < tgt)
        __builtin_amdgcn_s_sleep(2);
    }
    __syncthreads();
  }
}

// ---- batched out-projection: pred[b][i][:] = hbuf[i][b,:] @ Wout + bout
// for all 25 i at once. 800 blocks (25 i x 32 row-tiles) x 384 thr (6 waves = 6 bn).
__global__ __launch_bounds__(384)
void k_pred(const u16* __restrict__ hbase, const u16* __restrict__ WoT,
            const float* __restrict__ bout, float* __restrict__ pred){
  int blk = blockIdx.x;
  int i = blk >> 5, rbt = blk & 31;       // i in [0,25), row-tile in [0,32)
  int tid = threadIdx.x;
  int lane = tid & 63, bn = tid >> 6;     // wave index = bn in [0,6)
  int l16 = lane & 15, lk = lane >> 4;
  const short8* Aq = (const short8*)(hbase + (size_t)i*HSZ)
                     + (size_t)rbt*2048 + l16*4 + lk;
  const short8* Bq = (const short8*)WoT + (size_t)(bn*16 + l16)*128 + lk;
  f32x4 acc = {0.f,0.f,0.f,0.f};
  #pragma unroll 8
  for (int kit = 0; kit < 32; kit++)
    acc = __builtin_amdgcn_mfma_f32_16x16x32_bf16(Aq[kit*64], Bq[kit*4], acc, 0,0,0);
  int c = bn*16 + l16;
  float bb = bout[c];
  #pragma unroll
  for (int j=0;j<4;j++){
    int row = rbt*16 + lk*4 + j;
    pred[(size_t)row*2400 + (size_t)i*96 + c] = acc[j] + bb;
  }
}

extern "C" void kernel_launch(void* const* d_in, const int* in_sizes, int n_in,
                              void* d_out, int out_size, void* d_ws, size_t ws_size,
                              hipStream_t stream){
  // inputs: 0 enc_in, 1 dec_in, 2..5 enc_* (DEAD CODE), 6 dec_Wih, 7 dec_Whh,
  //         8 dec_bih, 9 dec_bhh, 10 W_out, 11 b_out
  const float* dec_in = (const float*)d_in[1];
  const float* Wih  = (const float*)d_in[6];
  const float* Whh  = (const float*)d_in[7];
  const float* bih  = (const float*)d_in[8];
  const float* bhh  = (const float*)d_in[9];
  const float* Wout = (const float*)d_in[10];
  const float* bout = (const float*)d_in[11];
  float* pred = (float*)d_out;   // [512][25][96] fp32

  char* ws = (char*)d_ws;
  size_t off = 0;
  u16* Wcp = (u16*)(ws + off);   off += (size_t)CTB*48*1024*2;     // 12.58 MB
  u16* WoT = (u16*)(ws + off);   off += (size_t)96*1024*2;
  float* cbias = (float*)(ws + off); off += (size_t)6144*4;
  off = (off + 255) & ~(size_t)255;
  float* hf0 = (float*)(ws + off); off += (size_t)BB*HH*4;   // col-major f32 carry seed
  u16* hbase = (u16*)(ws + off);   off += (size_t)TT*HSZ*2;  // 25 write-once bf16 buffers
  off = (off + 255) & ~(size_t)255;
  unsigned* flags = (unsigned*)(ws + off); off += 1024;

  k_prep_cast<<<3168, 256, 0, stream>>>(Whh, bhh, Wout, Wcp, cbias, WoT);
  k_prep_wx  <<<1536, 256, 0, stream>>>(Wih, Wout, Wcp);
  k_prep_cx  <<<12,   256, 0, stream>>>(Wih, bih, bout, cbias);
  k_step0    <<<128,  256, 0, stream>>>(dec_in, Wih, bih, bhh, hf0, hbase, flags);

  const float* hf0_c = hf0;
  void* kargs[] = {(void*)&hf0_c, (void*)&hbase, (void*)&Wcp, (void*)&cbias,
                   (void*)&flags};
  hipLaunchCooperativeKernel((const void*)k_persist6, dim3(256), dim3(256),
                             kargs, 0, stream);

  k_pred<<<800, 384, 0, stream>>>(hbase, WoT, bout, pred);
}

// Round 10
// 558.646 us; speedup vs baseline: 1.0783x; 1.0075x over previous
//
#include <hip/hip_runtime.h>
#include <hip/hip_bf16.h>

typedef __attribute__((ext_vector_type(8))) short short8;
typedef __attribute__((ext_vector_type(4))) float f32x4;
typedef __attribute__((ext_vector_type(4))) unsigned u32x4;
typedef unsigned short u16;

// Problem constants
#define BB 512     // batch
#define HH 1024    // hidden
#define TT 25      // decoder steps
#define CTB 128    // ct slices (each owns 8 hidden cols -> 48 Wc rows)
#define HSZ (BB*HH)   // elements in one h_bf buffer

// h_bf layout (A-frag tiled, per buffer): u16 index of (b, j) =
//   ((b>>4)*32 + (j>>5))*512 + (b&15)*32 + (j&31)
// -> one MFMA A-frag (16 rows x 32 cols) is a contiguous aligned 1 KB block.

__device__ __forceinline__ float sigm(float x){ return 1.f/(1.f+__expf(-x)); }
__device__ __forceinline__ float tanh_(float x){
  float e = __expf(-2.f*fabsf(x));
  float t = (1.f-e)/(1.f+e);
  return copysignf(t, x);
}
__device__ __forceinline__ u16 f2bf(float x){
  union { float f; unsigned u; } v; v.f = x;
  unsigned r = v.u + 0x7FFFu + ((v.u>>16)&1u);
  return (u16)(r>>16);
}
// 16B write-through store (visible at coherence point after vmcnt drain)
__device__ __forceinline__ void store16_wt(void* p, u32x4 v){
  asm volatile("global_store_dwordx4 %0, %1, off sc0 sc1" :: "v"(p), "v"(v) : "memory");
}

#if __has_builtin(__builtin_amdgcn_global_load_lds)
#define GLOAD_LDS16(g, l) __builtin_amdgcn_global_load_lds( \
    (const __attribute__((address_space(1))) void*)(g), \
    (__attribute__((address_space(3))) void*)(l), 16, 0, 0)
#define HAVE_GLL 1
#else
#define HAVE_GLL 0
#endif

// Wcp layout: per ct slice (8 hidden cols), 48 rows (r = gate*8 + u, gates:
// 0=gir 1=giz 2=gin 3=ghr 4=ghz 5=ghn), pre-packed in MFMA B-frag order:
// elem idx = ct*49152 + ((kit*3 + nf)*64 + lane)*8 + e
__device__ __forceinline__ size_t wc_idx(int ct, int r, int k){
  int nf = r>>4, rl = r&15, kit = k>>5, k31 = k&31;
  int lane = rl | (((k31>>3)&3)<<4);
  return (size_t)ct*49152 + ((size_t)(kit*3+nf)*64 + (size_t)lane)*8 + (k31&7);
}

// ================= merged prep kernel (one launch) =================
// blocks [0,1536): wx | [1536,4704): cast | [4704,4716): cx | [4716,4844): step0

__device__ void prep_wx_body(int bid, float* smem,
                             const float* __restrict__ Wih,
                             const float* __restrict__ Wout,
                             u16* __restrict__ Wcp){
  float (*sWih)[97] = (float(*)[97])smem;            // 32*97
  float (*sWo)[97]  = (float(*)[97])(smem + 32*97);  // 64*97
  int tid = threadIdx.x;
  int nt = bid % 96, kt = bid / 96;   // n-tile 32, k-tile 64
  for (int i = tid; i < 32*96; i += 256){ int r2=i/96, d=i%96; sWih[r2][d] = Wih[(size_t)(nt*32+r2)*96 + d]; }
  for (int i = tid; i < 64*96; i += 256){ int r2=i/96, d=i%96; sWo[r2][d]  = Wout[(size_t)(kt*64+r2)*96 + d]; }
  __syncthreads();
  int ni = tid & 31, kb = tid >> 5;    // thread owns 8 consecutive k
  float acc[8];
  #pragma unroll
  for (int i=0;i<8;i++) acc[i]=0.f;
  for (int d = 0; d < 96; d++){
    float a = sWih[ni][d];
    #pragma unroll
    for (int i=0;i<8;i++) acc[i] += a * sWo[kb*8 + i][d];
  }
  int n = nt*32 + ni;
  int g = n >> 10, j = n & 1023;
  int ct = j >> 3, u = j & 7, r = g*8 + u;
  size_t base = wc_idx(ct, r, kt*64 + kb*8);
  #pragma unroll
  for (int i=0;i<8;i++) Wcp[base+i] = f2bf(acc[i]);
}

__device__ void prep_cast_body(int bid,
                               const float* __restrict__ Whh, const float* __restrict__ bhh,
                               const float* __restrict__ Wout,
                               u16* __restrict__ Wcp, float* __restrict__ cbias,
                               u16* __restrict__ WoT){
  int tid = threadIdx.x;
  if (bid < 3072){
    int g1 = bid >> 10, j = bid & 1023;
    int ct = j >> 3, u = j & 7, r = (3+g1)*8 + u;
    const float* src = Whh + (size_t)bid*1024;
    if (tid < 128){
      int k0 = tid*8;
      size_t base = wc_idx(ct, r, k0);
      #pragma unroll
      for (int i=0;i<8;i++) Wcp[base+i] = f2bf(src[k0+i]);
    }
    if (!tid) cbias[ct*48 + r] = bhh[bid];
  } else {
    int d = bid - 3072;
    for (int k = tid; k < 1024; k += 256)
      WoT[(size_t)d*1024 + k] = f2bf(Wout[(size_t)k*96 + d]);
  }
}

__device__ void prep_cx_body(int bid,
                             const float* __restrict__ Wih, const float* __restrict__ bih,
                             const float* __restrict__ bout, float* __restrict__ cbias){
  int n = bid*256 + threadIdx.x;
  if (n >= 3072) return;
  float acc = bih[n];
  const float* wrow = Wih + (size_t)n*96;
  for (int d = 0; d < 96; d++) acc += bout[d]*wrow[d];
  int g = n >> 10, j = n & 1023;
  cbias[(j>>3)*48 + g*8 + (j&7)] = acc;
}

__device__ void step0_body(int bid, float* smem,
                           const float* __restrict__ dec_in, const float* __restrict__ Wih,
                           const float* __restrict__ bih, const float* __restrict__ bhh,
                           float* __restrict__ h_f32, u16* __restrict__ h_bf,
                           unsigned* __restrict__ flags){
  if (bid == 0 && threadIdx.x < 256) flags[threadIdx.x] = 0u;
  float (*sP)[97] = (float(*)[97])smem;            // 64*97
  float (*sW)[97] = (float(*)[97])(smem + 64*97);  // 64*97
  int tid = threadIdx.x;
  int bt = bid & 7;
  int jt = bid >> 3;
  for (int i = tid; i < 64*96; i += 256){ int r=i/96, d=i%96; sP[r][d] = dec_in[(size_t)(bt*64+r)*96 + d]; }
  int tb = tid >> 4, tj = tid & 15;
  float gg[3][4][4];
  for (int g = 0; g < 3; g++){
    __syncthreads();
    for (int i = tid; i < 64*96; i += 256){ int r=i/96, d=i%96; sW[r][d] = Wih[((size_t)g*1024 + jt*64 + r)*96 + d]; }
    __syncthreads();
    float acc[4][4];
    #pragma unroll
    for (int x=0;x<4;x++)
      #pragma unroll
      for (int y=0;y<4;y++) acc[x][y]=0.f;
    for (int d = 0; d < 96; d++){
      float a[4], wv[4];
      #pragma unroll
      for (int x=0;x<4;x++) a[x]  = sP[tb + x*16][d];
      #pragma unroll
      for (int y=0;y<4;y++) wv[y] = sW[tj + y*16][d];
      #pragma unroll
      for (int x=0;x<4;x++)
        #pragma unroll
        for (int y=0;y<4;y++) acc[x][y] += a[x]*wv[y];
    }
    #pragma unroll
    for (int x=0;x<4;x++)
      #pragma unroll
      for (int y=0;y<4;y++) gg[g][x][y] = acc[x][y];
  }
  #pragma unroll
  for (int x=0;x<4;x++)
    #pragma unroll
    for (int y=0;y<4;y++){
      int b = bt*64 + tb + x*16;
      int j = jt*64 + tj + y*16;
      float gir = gg[0][x][y] + bih[j];
      float giz = gg[1][x][y] + bih[1024+j];
      float gin = gg[2][x][y] + bih[2048+j];
      float r = sigm(gir + bhh[j]);
      float z = sigm(giz + bhh[1024+j]);
      float nn = tanh_(gin + r*bhh[2048+j]);
      float h = (1.f - z)*nn;
      h_f32[(size_t)j*512 + b] = h;
      h_bf[(size_t)(((b>>4)*32 + (j>>5))*512 + (b&15)*32 + (j&31))] = f2bf(h);
    }
}

__global__ __launch_bounds__(256)
void k_prep_all(const float* __restrict__ dec_in,
                const float* __restrict__ Wih, const float* __restrict__ Whh,
                const float* __restrict__ bih, const float* __restrict__ bhh,
                const float* __restrict__ Wout, const float* __restrict__ bout,
                u16* __restrict__ Wcp, float* __restrict__ cbias,
                u16* __restrict__ WoT,
                float* __restrict__ hf0, u16* __restrict__ hb0,
                unsigned* __restrict__ flags){
  __shared__ float smem[2*64*97];
  int bid = blockIdx.x;
  if (bid < 1536)            prep_wx_body(bid, smem, Wih, Wout, Wcp);
  else if (bid < 4704)       prep_cast_body(bid-1536, Whh, bhh, Wout, Wcp, cbias, WoT);
  else if (bid < 4716)       prep_cx_body(bid-4704, Wih, bih, bout, cbias);
  else                       step0_body(bid-4716, smem, dec_in, Wih, bih, bhh, hf0, hb0, flags);
}

// ---- persistent recurrence: A-stream via global_load_lds DMA ring (depth 3 kits),
// A/B reg double-buffer 1 kit ahead. 256 blk x 256 thr. (unchanged from round 9)
__global__ __launch_bounds__(256, 1)
void k_persist6(const float* __restrict__ hf0, u16* __restrict__ hbase,
                const u16* __restrict__ Wcp, const float* __restrict__ cbias,
                unsigned* __restrict__ flags){
  __shared__ short8 sB[6144];       // 96 KB: Wc slice, staged ONCE
  __shared__ short8 sA[4096];       // 64 KB: A ring [wave][slot(4)][frag(4)][64]
  int b = blockIdx.x, tid = threadIdx.x;
  int lane = tid & 63, w = tid >> 6;          // 4 waves
  int l16 = lane & 15, lk = lane >> 4;
  int r8 = b & 7;
  int bt = r8 >> 2;                           // batch half (XCDs 0-3 / 4-7)
  int ct = (b >> 3)*4 + (r8 & 3);             // slice [0,128)

  const short8* Wblk = (const short8*)Wcp + (size_t)ct*6144;
#if HAVE_GLL
  #pragma unroll
  for (int it = 0; it < 24; it++){
    int i = it*256 + tid;
    GLOAD_LDS16(Wblk + i, &sB[i]);
  }
#else
  for (int i = tid; i < 6144; i += 256) sB[i] = Wblk[i];
#endif

  float c0 = cbias[ct*48 +  0 + l16];
  float c1 = cbias[ct*48 + 16 + l16];
  float c2 = cbias[ct*48 + 32 + l16];
  bool hiB = (l16 & 8) != 0;
  int rowA = bt*256 + w*64;                   // wave owns 64 batch rows
  int rb0 = rowA >> 4;                        // first A-frag row-group
  int myFlag = bt*128 + ct;
  short8* sAw = &sA[w*1024];                  // wave's 16 KB ring
  int aswz = (l16<<2) | lk;                   // pre-swizzled DMA source lane offset

  // f32 carry in registers (this block's own 8 cols x its 64 rows)
  float hold[4][4];
  if (!hiB){
    int colg = ct*8 + l16;                    // l16 < 8 here
    #pragma unroll
    for (int mf = 0; mf < 4; mf++){
      f32x4 h4 = *(const f32x4*)(hf0 + (size_t)colg*512 + rowA + mf*16 + lk*4);
      hold[mf][0]=h4[0]; hold[mf][1]=h4[1]; hold[mf][2]=h4[2]; hold[mf][3]=h4[3];
    }
  }
  __syncthreads();   // Wc staging complete

  for (int t = 1; t <= 24; ++t){
    const short8* pin8 = (const short8*)(hbase + (size_t)(t-1)*HSZ);
    u16* pout = hbase + (size_t)t*HSZ;
    const short8* Afrag = pin8 + (size_t)rb0*2048 + aswz;

#if HAVE_GLL
    #define DMA_KIT(k, s) { \
      GLOAD_LDS16(Afrag + 0*2048 + (k)*64, sAw + (s)*256 + 0*64); \
      GLOAD_LDS16(Afrag + 1*2048 + (k)*64, sAw + (s)*256 + 1*64); \
      GLOAD_LDS16(Afrag + 2*2048 + (k)*64, sAw + (s)*256 + 2*64); \
      GLOAD_LDS16(Afrag + 3*2048 + (k)*64, sAw + (s)*256 + 3*64); }
#else
    #define DMA_KIT(k, s) { \
      sAw[(s)*256 + 0*64 + lane] = Afrag[0*2048 + (k)*64 - aswz + lane]; \
      sAw[(s)*256 + 1*64 + lane] = Afrag[1*2048 + (k)*64 - aswz + lane]; \
      sAw[(s)*256 + 2*64 + lane] = Afrag[2*2048 + (k)*64 - aswz + lane]; \
      sAw[(s)*256 + 3*64 + lane] = Afrag[3*2048 + (k)*64 - aswz + lane]; }
#endif

    // prologue: DMA kits 0,1,2 into slots 0,1,2
    DMA_KIT(0, 0); DMA_KIT(1, 1); DMA_KIT(2, 2);
    asm volatile("s_waitcnt vmcnt(8)" ::: "memory");   // kit0 arrived
    __builtin_amdgcn_sched_barrier(0);

    short8 araw[2][4], brw[2][3];
    #pragma unroll
    for (int m = 0; m < 4; m++) araw[0][m] = sAw[m*64 + lane];
    #pragma unroll
    for (int nf = 0; nf < 3; nf++) brw[0][nf] = sB[nf*64 + lane];

    f32x4 acc[4][3];
    #pragma unroll
    for (int m=0;m<4;m++)
      #pragma unroll
      for (int nf=0;nf<3;nf++) acc[m][nf] = f32x4{0.f,0.f,0.f,0.f};

    #pragma unroll
    for (int kit = 0; kit < 32; kit++){
      const int cur = kit & 1, nxt = cur ^ 1;
      if (kit < 31){
        if (kit < 30) asm volatile("s_waitcnt vmcnt(4)" ::: "memory");
        else          asm volatile("s_waitcnt vmcnt(0)" ::: "memory");
        __builtin_amdgcn_sched_barrier(0);
        const int s1 = (kit+1) & 3;
        #pragma unroll
        for (int m = 0; m < 4; m++) araw[nxt][m] = sAw[s1*256 + m*64 + lane];
        #pragma unroll
        for (int nf = 0; nf < 3; nf++) brw[nxt][nf] = sB[(kit+1)*192 + nf*64 + lane];
      }
      if (kit < 29) DMA_KIT(kit+3, (kit+3) & 3);
      acc[0][0] = __builtin_amdgcn_mfma_f32_16x16x32_bf16(araw[cur][0], brw[cur][0], acc[0][0], 0,0,0);
      acc[1][0] = __builtin_amdgcn_mfma_f32_16x16x32_bf16(araw[cur][1], brw[cur][0], acc[1][0], 0,0,0);
      acc[2][0] = __builtin_amdgcn_mfma_f32_16x16x32_bf16(araw[cur][2], brw[cur][0], acc[2][0], 0,0,0);
      acc[3][0] = __builtin_amdgcn_mfma_f32_16x16x32_bf16(araw[cur][3], brw[cur][0], acc[3][0], 0,0,0);
      acc[0][1] = __builtin_amdgcn_mfma_f32_16x16x32_bf16(araw[cur][0], brw[cur][1], acc[0][1], 0,0,0);
      acc[1][1] = __builtin_amdgcn_mfma_f32_16x16x32_bf16(araw[cur][1], brw[cur][1], acc[1][1], 0,0,0);
      acc[2][1] = __builtin_amdgcn_mfma_f32_16x16x32_bf16(araw[cur][2], brw[cur][1], acc[2][1], 0,0,0);
      acc[3][1] = __builtin_amdgcn_mfma_f32_16x16x32_bf16(araw[cur][3], brw[cur][1], acc[3][1], 0,0,0);
      acc[0][2] = __builtin_amdgcn_mfma_f32_16x16x32_bf16(araw[cur][0], brw[cur][2], acc[0][2], 0,0,0);
      acc[1][2] = __builtin_amdgcn_mfma_f32_16x16x32_bf16(araw[cur][1], brw[cur][2], acc[1][2], 0,0,0);
      acc[2][2] = __builtin_amdgcn_mfma_f32_16x16x32_bf16(araw[cur][2], brw[cur][2], acc[2][2], 0,0,0);
      acc[3][2] = __builtin_amdgcn_mfma_f32_16x16x32_bf16(araw[cur][3], brw[cur][2], acc[3][2], 0,0,0);
    }
    #undef DMA_KIT

    // ---- gates via lane pair (l, l^8); lo: gir,gin,ghz  hi: giz,ghr,ghn
    #pragma unroll
    for (int mf=0; mf<4; mf++){
      #pragma unroll
      for (int j=0;j<4;j++){
        float g0 = acc[mf][0][j] + c0;
        float g1 = acc[mf][1][j] + c1;
        float g2 = acc[mf][2][j] + c2;
        float v1 = hiB ? g1 : g2;
        float w1 = __shfl_xor(v1, 8, 64);
        float rz = sigm(g0 + w1);
        float w2 = __shfl_xor(rz, 8, 64);
        float v3 = hiB ? (w2 * g2) : 0.f;
        float w3 = __shfl_xor(v3, 8, 64);
        float hnew = 0.f;
        if (!hiB){
          float nn = tanh_(g1 + w3);
          hnew = (1.f - w2)*nn + w2*hold[mf][j];
          hold[mf][j] = hnew;
        }
        float o1 = __shfl_xor(hnew, 1, 64);
        unsigned pk = ((unsigned)f2bf(o1) << 16) | (unsigned)f2bf(hnew);
        unsigned pk2 = __shfl_xor(pk, 2, 64);
        unsigned q2 = __shfl_xor(pk, 4, 64);
        unsigned q3 = __shfl_xor(pk2, 4, 64);
        if (l16 == 0){
          u32x4 vv = {pk, pk2, q2, q3};
          store16_wt((char*)pout + (size_t)(rb0+mf)*32768 + (size_t)(ct>>2)*1024
                                 + (size_t)(lk*4+j)*64 + (size_t)(ct&3)*16, vv);
        }
      }
    }

    // ---- fence-free barrier
    __syncthreads();   // drains every wave's stores+DMA (vmcnt 0 before s_barrier)
    if (tid == 0)
      __hip_atomic_store(&flags[myFlag], (unsigned)t,
                         __ATOMIC_RELAXED, __HIP_MEMORY_SCOPE_AGENT);
    if (tid < 128){
      unsigned tgt = (unsigned)t;
      while (__hip_atomic_load(&flags[bt*128 + tid], __ATOMIC_RELAXED,
                               __HIP_MEMORY_SCOPE_AGENT) < tgt)
        __builtin_amdgcn_s_sleep(2);
    }
    __syncthreads();
  }
}

// ---- batched out-projection: pred[b][i][:] = hbuf[i][b,:] @ Wout + bout
__global__ __launch_bounds__(384)
void k_pred(const u16* __restrict__ hbase, const u16* __restrict__ WoT,
            const float* __restrict__ bout, float* __restrict__ pred){
  int blk = blockIdx.x;
  int i = blk >> 5, rbt = blk & 31;       // i in [0,25), row-tile in [0,32)
  int tid = threadIdx.x;
  int lane = tid & 63, bn = tid >> 6;     // wave index = bn in [0,6)
  int l16 = lane & 15, lk = lane >> 4;
  const short8* Aq = (const short8*)(hbase + (size_t)i*HSZ)
                     + (size_t)rbt*2048 + l16*4 + lk;
  const short8* Bq = (const short8*)WoT + (size_t)(bn*16 + l16)*128 + lk;
  f32x4 acc = {0.f,0.f,0.f,0.f};
  #pragma unroll 8
  for (int kit = 0; kit < 32; kit++)
    acc = __builtin_amdgcn_mfma_f32_16x16x32_bf16(Aq[kit*64], Bq[kit*4], acc, 0,0,0);
  int c = bn*16 + l16;
  float bb = bout[c];
  #pragma unroll
  for (int j=0;j<4;j++){
    int row = rbt*16 + lk*4 + j;
    pred[(size_t)row*2400 + (size_t)i*96 + c] = acc[j] + bb;
  }
}

extern "C" void kernel_launch(void* const* d_in, const int* in_sizes, int n_in,
                              void* d_out, int out_size, void* d_ws, size_t ws_size,
                              hipStream_t stream){
  // inputs: 0 enc_in, 1 dec_in, 2..5 enc_* (DEAD CODE), 6 dec_Wih, 7 dec_Whh,
  //         8 dec_bih, 9 dec_bhh, 10 W_out, 11 b_out
  const float* dec_in = (const float*)d_in[1];
  const float* Wih  = (const float*)d_in[6];
  const float* Whh  = (const float*)d_in[7];
  const float* bih  = (const float*)d_in[8];
  const float* bhh  = (const float*)d_in[9];
  const float* Wout = (const float*)d_in[10];
  const float* bout = (const float*)d_in[11];
  float* pred = (float*)d_out;   // [512][25][96] fp32

  char* ws = (char*)d_ws;
  size_t off = 0;
  u16* Wcp = (u16*)(ws + off);   off += (size_t)CTB*48*1024*2;     // 12.58 MB
  u16* WoT = (u16*)(ws + off);   off += (size_t)96*1024*2;
  float* cbias = (float*)(ws + off); off += (size_t)6144*4;
  off = (off + 255) & ~(size_t)255;
  float* hf0 = (float*)(ws + off); off += (size_t)BB*HH*4;   // col-major f32 carry seed
  u16* hbase = (u16*)(ws + off);   off += (size_t)TT*HSZ*2;  // 25 write-once bf16 buffers
  off = (off + 255) & ~(size_t)255;
  unsigned* flags = (unsigned*)(ws + off); off += 1024;

  k_prep_all<<<4844, 256, 0, stream>>>(dec_in, Wih, Whh, bih, bhh, Wout, bout,
                                       Wcp, cbias, WoT, hf0, hbase, flags);

  const float* hf0_c = hf0;
  void* kargs[] = {(void*)&hf0_c, (void*)&hbase, (void*)&Wcp, (void*)&cbias,
                   (void*)&flags};
  hipLaunchCooperativeKernel((const void*)k_persist6, dim3(256), dim3(256),
                             kargs, 0, stream);

  k_pred<<<800, 384, 0, stream>>>(hbase, WoT, bout, pred);
}

// Round 11
// 526.433 us; speedup vs baseline: 1.1443x; 1.0612x over previous
//
#include <hip/hip_runtime.h>
#include <hip/hip_bf16.h>

typedef __attribute__((ext_vector_type(8))) short short8;
typedef __attribute__((ext_vector_type(4))) float f32x4;
typedef __attribute__((ext_vector_type(4))) unsigned u32x4;
typedef unsigned short u16;

// Problem constants
#define BB 512     // batch
#define HH 1024    // hidden
#define TT 25      // decoder steps
#define CTB 128    // ct slices (each owns 8 hidden cols -> 48 Wc rows)
#define HSZ (BB*HH)   // elements in one h_bf buffer

// h_bf layout (A-frag tiled, per buffer): u16 index of (b, j) =
//   ((b>>4)*32 + (j>>5))*512 + (b&15)*32 + (j&31)
// -> one MFMA A-frag (16 rows x 32 cols) is a contiguous aligned 1 KB block.

__device__ __forceinline__ float sigm(float x){ return 1.f/(1.f+__expf(-x)); }
__device__ __forceinline__ float tanh_(float x){
  float e = __expf(-2.f*fabsf(x));
  float t = (1.f-e)/(1.f+e);
  return copysignf(t, x);
}
__device__ __forceinline__ u16 f2bf(float x){
  union { float f; unsigned u; } v; v.f = x;
  unsigned r = v.u + 0x7FFFu + ((v.u>>16)&1u);
  return (u16)(r>>16);
}
// 16B write-through store (visible at coherence point after vmcnt drain)
__device__ __forceinline__ void store16_wt(void* p, u32x4 v){
  asm volatile("global_store_dwordx4 %0, %1, off sc0 sc1" :: "v"(p), "v"(v) : "memory");
}
// un-sinkable 16B load into explicit VGPRs (completion via manual s_waitcnt)
__device__ __forceinline__ void aload(short8 &d, const short8* p){
  asm volatile("global_load_dwordx4 %0, %1, off" : "=v"(d) : "v"(p));
}

#if __has_builtin(__builtin_amdgcn_global_load_lds)
#define GLOAD_LDS16(g, l) __builtin_amdgcn_global_load_lds( \
    (const __attribute__((address_space(1))) void*)(g), \
    (__attribute__((address_space(3))) void*)(l), 16, 0, 0)
#define HAVE_GLL 1
#else
#define HAVE_GLL 0
#endif

// Wcp layout: per ct slice (8 hidden cols), 48 rows (r = gate*8 + u, gates:
// 0=gir 1=giz 2=gin 3=ghr 4=ghz 5=ghn), pre-packed in MFMA B-frag order:
// elem idx = ct*49152 + ((kit*3 + nf)*64 + lane)*8 + e
__device__ __forceinline__ size_t wc_idx(int ct, int r, int k){
  int nf = r>>4, rl = r&15, kit = k>>5, k31 = k&31;
  int lane = rl | (((k31>>3)&3)<<4);
  return (size_t)ct*49152 + ((size_t)(kit*3+nf)*64 + (size_t)lane)*8 + (k31&7);
}

// ================= merged prep kernel (one launch) =================
// blocks [0,1536): wx | [1536,4704): cast | [4704,4716): cx | [4716,4844): step0

__device__ void prep_wx_body(int bid, float* smem,
                             const float* __restrict__ Wih,
                             const float* __restrict__ Wout,
                             u16* __restrict__ Wcp){
  float (*sWih)[97] = (float(*)[97])smem;            // 32*97
  float (*sWo)[97]  = (float(*)[97])(smem + 32*97);  // 64*97
  int tid = threadIdx.x;
  int nt = bid % 96, kt = bid / 96;   // n-tile 32, k-tile 64
  for (int i = tid; i < 32*96; i += 256){ int r2=i/96, d=i%96; sWih[r2][d] = Wih[(size_t)(nt*32+r2)*96 + d]; }
  for (int i = tid; i < 64*96; i += 256){ int r2=i/96, d=i%96; sWo[r2][d]  = Wout[(size_t)(kt*64+r2)*96 + d]; }
  __syncthreads();
  int ni = tid & 31, kb = tid >> 5;    // thread owns 8 consecutive k
  float acc[8];
  #pragma unroll
  for (int i=0;i<8;i++) acc[i]=0.f;
  for (int d = 0; d < 96; d++){
    float a = sWih[ni][d];
    #pragma unroll
    for (int i=0;i<8;i++) acc[i] += a * sWo[kb*8 + i][d];
  }
  int n = nt*32 + ni;
  int g = n >> 10, j = n & 1023;
  int ct = j >> 3, u = j & 7, r = g*8 + u;
  size_t base = wc_idx(ct, r, kt*64 + kb*8);
  #pragma unroll
  for (int i=0;i<8;i++) Wcp[base+i] = f2bf(acc[i]);
}

__device__ void prep_cast_body(int bid,
                               const float* __restrict__ Whh, const float* __restrict__ bhh,
                               const float* __restrict__ Wout,
                               u16* __restrict__ Wcp, float* __restrict__ cbias,
                               u16* __restrict__ WoT){
  int tid = threadIdx.x;
  if (bid < 3072){
    int g1 = bid >> 10, j = bid & 1023;
    int ct = j >> 3, u = j & 7, r = (3+g1)*8 + u;
    const float* src = Whh + (size_t)bid*1024;
    if (tid < 128){
      int k0 = tid*8;
      size_t base = wc_idx(ct, r, k0);
      #pragma unroll
      for (int i=0;i<8;i++) Wcp[base+i] = f2bf(src[k0+i]);
    }
    if (!tid) cbias[ct*48 + r] = bhh[bid];
  } else {
    int d = bid - 3072;
    for (int k = tid; k < 1024; k += 256)
      WoT[(size_t)d*1024 + k] = f2bf(Wout[(size_t)k*96 + d]);
  }
}

__device__ void prep_cx_body(int bid,
                             const float* __restrict__ Wih, const float* __restrict__ bih,
                             const float* __restrict__ bout, float* __restrict__ cbias){
  int n = bid*256 + threadIdx.x;
  if (n >= 3072) return;
  float acc = bih[n];
  const float* wrow = Wih + (size_t)n*96;
  for (int d = 0; d < 96; d++) acc += bout[d]*wrow[d];
  int g = n >> 10, j = n & 1023;
  cbias[(j>>3)*48 + g*8 + (j&7)] = acc;
}

__device__ void step0_body(int bid, float* smem,
                           const float* __restrict__ dec_in, const float* __restrict__ Wih,
                           const float* __restrict__ bih, const float* __restrict__ bhh,
                           float* __restrict__ h_f32, u16* __restrict__ h_bf,
                           unsigned* __restrict__ flags){
  if (bid == 0 && threadIdx.x < 256) flags[threadIdx.x] = 0u;
  float (*sP)[97] = (float(*)[97])smem;            // 64*97
  float (*sW)[97] = (float(*)[97])(smem + 64*97);  // 64*97
  int tid = threadIdx.x;
  int bt = bid & 7;
  int jt = bid >> 3;
  for (int i = tid; i < 64*96; i += 256){ int r=i/96, d=i%96; sP[r][d] = dec_in[(size_t)(bt*64+r)*96 + d]; }
  int tb = tid >> 4, tj = tid & 15;
  float gg[3][4][4];
  for (int g = 0; g < 3; g++){
    __syncthreads();
    for (int i = tid; i < 64*96; i += 256){ int r=i/96, d=i%96; sW[r][d] = Wih[((size_t)g*1024 + jt*64 + r)*96 + d]; }
    __syncthreads();
    float acc[4][4];
    #pragma unroll
    for (int x=0;x<4;x++)
      #pragma unroll
      for (int y=0;y<4;y++) acc[x][y]=0.f;
    for (int d = 0; d < 96; d++){
      float a[4], wv[4];
      #pragma unroll
      for (int x=0;x<4;x++) a[x]  = sP[tb + x*16][d];
      #pragma unroll
      for (int y=0;y<4;y++) wv[y] = sW[tj + y*16][d];
      #pragma unroll
      for (int x=0;x<4;x++)
        #pragma unroll
        for (int y=0;y<4;y++) acc[x][y] += a[x]*wv[y];
    }
    #pragma unroll
    for (int x=0;x<4;x++)
      #pragma unroll
      for (int y=0;y<4;y++) gg[g][x][y] = acc[x][y];
  }
  #pragma unroll
  for (int x=0;x<4;x++)
    #pragma unroll
    for (int y=0;y<4;y++){
      int b = bt*64 + tb + x*16;
      int j = jt*64 + tj + y*16;
      float gir = gg[0][x][y] + bih[j];
      float giz = gg[1][x][y] + bih[1024+j];
      float gin = gg[2][x][y] + bih[2048+j];
      float r = sigm(gir + bhh[j]);
      float z = sigm(giz + bhh[1024+j]);
      float nn = tanh_(gin + r*bhh[2048+j]);
      float h = (1.f - z)*nn;
      h_f32[(size_t)j*512 + b] = h;
      h_bf[(size_t)(((b>>4)*32 + (j>>5))*512 + (b&15)*32 + (j&31))] = f2bf(h);
    }
}

__global__ __launch_bounds__(256)
void k_prep_all(const float* __restrict__ dec_in,
                const float* __restrict__ Wih, const float* __restrict__ Whh,
                const float* __restrict__ bih, const float* __restrict__ bhh,
                const float* __restrict__ Wout, const float* __restrict__ bout,
                u16* __restrict__ Wcp, float* __restrict__ cbias,
                u16* __restrict__ WoT,
                float* __restrict__ hf0, u16* __restrict__ hb0,
                unsigned* __restrict__ flags){
  __shared__ float smem[2*64*97];
  int bid = blockIdx.x;
  if (bid < 1536)            prep_wx_body(bid, smem, Wih, Wout, Wcp);
  else if (bid < 4704)       prep_cast_body(bid-1536, Whh, bhh, Wout, Wcp, cbias, WoT);
  else if (bid < 4716)       prep_cx_body(bid-4704, Wih, bih, bout, cbias);
  else                       step0_body(bid-4716, smem, dec_in, Wih, bih, bhh, hf0, hb0, flags);
}

// ---- persistent recurrence: A-stream in REGISTERS via inline-asm load ring
// (depth 4 kits = 16 loads in flight, steady-state s_waitcnt vmcnt(12)).
// B in LDS (96 KB, staged once). 256 blk x 256 thr (4 waves, 1/SIMD).
__global__ __launch_bounds__(256, 1)
void k_persist7(const float* __restrict__ hf0, u16* __restrict__ hbase,
                const u16* __restrict__ Wcp, const float* __restrict__ cbias,
                unsigned* __restrict__ flags){
  __shared__ short8 sB[6144];       // 96 KB: Wc slice, staged ONCE
  int b = blockIdx.x, tid = threadIdx.x;
  int lane = tid & 63, w = tid >> 6;          // 4 waves
  int l16 = lane & 15, lk = lane >> 4;
  int r8 = b & 7;
  int bt = r8 >> 2;                           // batch half (XCDs 0-3 / 4-7)
  int ct = (b >> 3)*4 + (r8 & 3);             // slice [0,128)

  const short8* Wblk = (const short8*)Wcp + (size_t)ct*6144;
#if HAVE_GLL
  #pragma unroll
  for (int it = 0; it < 24; it++){
    int i = it*256 + tid;
    GLOAD_LDS16(Wblk + i, &sB[i]);
  }
#else
  for (int i = tid; i < 6144; i += 256) sB[i] = Wblk[i];
#endif

  float c0 = cbias[ct*48 +  0 + l16];
  float c1 = cbias[ct*48 + 16 + l16];
  float c2 = cbias[ct*48 + 32 + l16];
  bool hiB = (l16 & 8) != 0;
  int rowA = bt*256 + w*64;                   // wave owns 64 batch rows
  int rb0 = rowA >> 4;                        // first A-frag row-group
  int myFlag = bt*128 + ct;

  // f32 carry in registers (this block's own 8 cols x its 64 rows)
  float hold[4][4];
  if (!hiB){
    int colg = ct*8 + l16;                    // l16 < 8 here
    #pragma unroll
    for (int mf = 0; mf < 4; mf++){
      f32x4 h4 = *(const f32x4*)(hf0 + (size_t)colg*512 + rowA + mf*16 + lk*4);
      hold[mf][0]=h4[0]; hold[mf][1]=h4[1]; hold[mf][2]=h4[2]; hold[mf][3]=h4[3];
    }
  }
  __syncthreads();   // Wc staging complete

  for (int t = 1; t <= 24; ++t){
    const short8* pin8 = (const short8*)(hbase + (size_t)(t-1)*HSZ);
    u16* pout = hbase + (size_t)t*HSZ;
    // per-lane A address: frag m, kit k at Ap + m*2048 + k*64 (16B units)
    const short8* Ap = pin8 + (size_t)rb0*2048 + l16*4 + lk;

    short8 ar[4][4];   // [slot][m] — explicit asm-defined VGPRs, un-sinkable
    #define AISSUE(k, s) { \
      aload(ar[s][0], Ap + 0*2048 + (k)*64); \
      aload(ar[s][1], Ap + 1*2048 + (k)*64); \
      aload(ar[s][2], Ap + 2*2048 + (k)*64); \
      aload(ar[s][3], Ap + 3*2048 + (k)*64); }

    // prologue: kits 0..3 in flight (16 loads)
    AISSUE(0,0); AISSUE(1,1); AISSUE(2,2); AISSUE(3,3);

    short8 brw[2][3];
    #pragma unroll
    for (int nf = 0; nf < 3; nf++) brw[0][nf] = sB[nf*64 + lane];

    f32x4 acc[4][3];
    #pragma unroll
    for (int m=0;m<4;m++)
      #pragma unroll
      for (int nf=0;nf<3;nf++) acc[m][nf] = f32x4{0.f,0.f,0.f,0.f};

    #pragma unroll
    for (int kit = 0; kit < 32; kit++){
      const int cur = kit & 1, nxt = cur ^ 1, sa = kit & 3;
      // wait for kit's 4 loads: outstanding beyond them <= N
      if (kit <= 28)      asm volatile("s_waitcnt vmcnt(12)" ::: "memory");
      else if (kit == 29) asm volatile("s_waitcnt vmcnt(8)"  ::: "memory");
      else if (kit == 30) asm volatile("s_waitcnt vmcnt(4)"  ::: "memory");
      else                asm volatile("s_waitcnt vmcnt(0)"  ::: "memory");
      __builtin_amdgcn_sched_barrier(0);
      if (kit < 31){
        #pragma unroll
        for (int nf = 0; nf < 3; nf++) brw[nxt][nf] = sB[(kit+1)*192 + nf*64 + lane];
      }
      acc[0][0] = __builtin_amdgcn_mfma_f32_16x16x32_bf16(ar[sa][0], brw[cur][0], acc[0][0], 0,0,0);
      acc[1][0] = __builtin_amdgcn_mfma_f32_16x16x32_bf16(ar[sa][1], brw[cur][0], acc[1][0], 0,0,0);
      acc[2][0] = __builtin_amdgcn_mfma_f32_16x16x32_bf16(ar[sa][2], brw[cur][0], acc[2][0], 0,0,0);
      acc[3][0] = __builtin_amdgcn_mfma_f32_16x16x32_bf16(ar[sa][3], brw[cur][0], acc[3][0], 0,0,0);
      acc[0][1] = __builtin_amdgcn_mfma_f32_16x16x32_bf16(ar[sa][0], brw[cur][1], acc[0][1], 0,0,0);
      acc[1][1] = __builtin_amdgcn_mfma_f32_16x16x32_bf16(ar[sa][1], brw[cur][1], acc[1][1], 0,0,0);
      acc[2][1] = __builtin_amdgcn_mfma_f32_16x16x32_bf16(ar[sa][2], brw[cur][1], acc[2][1], 0,0,0);
      acc[3][1] = __builtin_amdgcn_mfma_f32_16x16x32_bf16(ar[sa][3], brw[cur][1], acc[3][1], 0,0,0);
      acc[0][2] = __builtin_amdgcn_mfma_f32_16x16x32_bf16(ar[sa][0], brw[cur][2], acc[0][2], 0,0,0);
      acc[1][2] = __builtin_amdgcn_mfma_f32_16x16x32_bf16(ar[sa][1], brw[cur][2], acc[1][2], 0,0,0);
      acc[2][2] = __builtin_amdgcn_mfma_f32_16x16x32_bf16(ar[sa][2], brw[cur][2], acc[2][2], 0,0,0);
      acc[3][2] = __builtin_amdgcn_mfma_f32_16x16x32_bf16(ar[sa][3], brw[cur][2], acc[3][2], 0,0,0);
      if (kit < 28) AISSUE(kit+4, sa);
    }
    #undef AISSUE

    // ---- gates via lane pair (l, l^8); lo: gir,gin,ghz  hi: giz,ghr,ghn
    #pragma unroll
    for (int mf=0; mf<4; mf++){
      #pragma unroll
      for (int j=0;j<4;j++){
        float g0 = acc[mf][0][j] + c0;
        float g1 = acc[mf][1][j] + c1;
        float g2 = acc[mf][2][j] + c2;
        float v1 = hiB ? g1 : g2;
        float w1 = __shfl_xor(v1, 8, 64);
        float rz = sigm(g0 + w1);
        float w2 = __shfl_xor(rz, 8, 64);
        float v3 = hiB ? (w2 * g2) : 0.f;
        float w3 = __shfl_xor(v3, 8, 64);
        float hnew = 0.f;
        if (!hiB){
          float nn = tanh_(g1 + w3);
          hnew = (1.f - w2)*nn + w2*hold[mf][j];
          hold[mf][j] = hnew;
        }
        float o1 = __shfl_xor(hnew, 1, 64);
        unsigned pk = ((unsigned)f2bf(o1) << 16) | (unsigned)f2bf(hnew);
        unsigned pk2 = __shfl_xor(pk, 2, 64);
        unsigned q2 = __shfl_xor(pk, 4, 64);
        unsigned q3 = __shfl_xor(pk2, 4, 64);
        if (l16 == 0){
          u32x4 vv = {pk, pk2, q2, q3};
          store16_wt((char*)pout + (size_t)(rb0+mf)*32768 + (size_t)(ct>>2)*1024
                                 + (size_t)(lk*4+j)*64 + (size_t)(ct&3)*16, vv);
        }
      }
    }

    // ---- fence-free barrier
    __syncthreads();   // drains every wave's stores (vmcnt 0 before s_barrier)
    if (tid == 0)
      __hip_atomic_store(&flags[myFlag], (unsigned)t,
                         __ATOMIC_RELAXED, __HIP_MEMORY_SCOPE_AGENT);
    if (tid < 128){
      unsigned tgt = (unsigned)t;
      while (__hip_atomic_load(&flags[bt*128 + tid], __ATOMIC_RELAXED,
                               __HIP_MEMORY_SCOPE_AGENT) < tgt)
        __builtin_amdgcn_s_sleep(2);
    }
    __syncthreads();
  }
}

// ---- batched out-projection: pred[b][i][:] = hbuf[i][b,:] @ Wout + bout
__global__ __launch_bounds__(384)
void k_pred(const u16* __restrict__ hbase, const u16* __restrict__ WoT,
            const float* __restrict__ bout, float* __restrict__ pred){
  int blk = blockIdx.x;
  int i = blk >> 5, rbt = blk & 31;       // i in [0,25), row-tile in [0,32)
  int tid = threadIdx.x;
  int lane = tid & 63, bn = tid >> 6;     // wave index = bn in [0,6)
  int l16 = lane & 15, lk = lane >> 4;
  const short8* Aq = (const short8*)(hbase + (size_t)i*HSZ)
                     + (size_t)rbt*2048 + l16*4 + lk;
  const short8* Bq = (const short8*)WoT + (size_t)(bn*16 + l16)*128 + lk;
  f32x4 acc = {0.f,0.f,0.f,0.f};
  #pragma unroll 8
  for (int kit = 0; kit < 32; kit++)
    acc = __builtin_amdgcn_mfma_f32_16x16x32_bf16(Aq[kit*64], Bq[kit*4], acc, 0,0,0);
  int c = bn*16 + l16;
  float bb = bout[c];
  #pragma unroll
  for (int j=0;j<4;j++){
    int row = rbt*16 + lk*4 + j;
    pred[(size_t)row*2400 + (size_t)i*96 + c] = acc[j] + bb;
  }
}

extern "C" void kernel_launch(void* const* d_in, const int* in_sizes, int n_in,
                              void* d_out, int out_size, void* d_ws, size_t ws_size,
                              hipStream_t stream){
  // inputs: 0 enc_in, 1 dec_in, 2..5 enc_* (DEAD CODE), 6 dec_Wih, 7 dec_Whh,
  //         8 dec_bih, 9 dec_bhh, 10 W_out, 11 b_out
  const float* dec_in = (const float*)d_in[1];
  const float* Wih  = (const float*)d_in[6];
  const float* Whh  = (const float*)d_in[7];
  const float* bih  = (const float*)d_in[8];
  const float* bhh  = (const float*)d_in[9];
  const float* Wout = (const float*)d_in[10];
  const float* bout = (const float*)d_in[11];
  float* pred = (float*)d_out;   // [512][25][96] fp32

  char* ws = (char*)d_ws;
  size_t off = 0;
  u16* Wcp = (u16*)(ws + off);   off += (size_t)CTB*48*1024*2;     // 12.58 MB
  u16* WoT = (u16*)(ws + off);   off += (size_t)96*1024*2;
  float* cbias = (float*)(ws + off); off += (size_t)6144*4;
  off = (off + 255) & ~(size_t)255;
  float* hf0 = (float*)(ws + off); off += (size_t)BB*HH*4;   // col-major f32 carry seed
  u16* hbase = (u16*)(ws + off);   off += (size_t)TT*HSZ*2;  // 25 write-once bf16 buffers
  off = (off + 255) & ~(size_t)255;
  unsigned* flags = (unsigned*)(ws + off); off += 1024;

  k_prep_all<<<4844, 256, 0, stream>>>(dec_in, Wih, Whh, bih, bhh, Wout, bout,
                                       Wcp, cbias, WoT, hf0, hbase, flags);

  const float* hf0_c = hf0;
  void* kargs[] = {(void*)&hf0_c, (void*)&hbase, (void*)&Wcp, (void*)&cbias,
                   (void*)&flags};
  hipLaunchCooperativeKernel((const void*)k_persist7, dim3(256), dim3(256),
                             kargs, 0, stream);

  k_pred<<<800, 384, 0, stream>>>(hbase, WoT, bout, pred);
}